// Round 7
// baseline (448.603 us; speedup 1.0000x reference)
//
#include <hip/hip_runtime.h>
#include <hip/hip_bf16.h>
#include <cstdint>
#include <cstddef>

typedef __hip_bfloat16 bf16;
typedef __attribute__((ext_vector_type(8))) short bfrag8;   // 8 bf16 = 4 VGPR
typedef __attribute__((ext_vector_type(4))) float f32x4;    // MFMA acc

// ---- bf16 bit helpers ------------------------------------------------------
__device__ __forceinline__ float bfu2f(unsigned int u16) {
    unsigned int w = u16 << 16;
    float f; __builtin_memcpy(&f, &w, 4); return f;
}
__device__ __forceinline__ unsigned short f2bfu(float f) {
    bf16 h = __float2bfloat16(f);
    unsigned short u; __builtin_memcpy(&u, &h, 2); return u;
}
__device__ __forceinline__ void unpk8(const uint4 u, float* f) {
    f[0] = bfu2f(u.x & 0xffffu); f[1] = bfu2f(u.x >> 16);
    f[2] = bfu2f(u.y & 0xffffu); f[3] = bfu2f(u.y >> 16);
    f[4] = bfu2f(u.z & 0xffffu); f[5] = bfu2f(u.z >> 16);
    f[6] = bfu2f(u.w & 0xffffu); f[7] = bfu2f(u.w >> 16);
}

// ---------------------------------------------------------------------------
// Weight prep: OIHW f32 -> MFMA A-fragment bf16 layout (3x3 convs).
// ---------------------------------------------------------------------------
struct WSrc { const float* w[9]; };

__global__ __launch_bounds__(256) void prep_k(WSrc src, bf16* __restrict__ wp) {
    const int l = blockIdx.x;
    const int CI[9]  = {16, 16, 16, 32, 32, 32, 32, 16, 16};
    const int CO[9]  = {16, 16, 32, 32, 32, 32, 16, 16, 16};
    const int OFF[9] = {0, 3072, 6144, 12288, 21504, 30720, 39936, 44544, 47616};
    const int cin = CI[l], cout = CO[l], nct = cout / 16;
    const int nt = (cin == 32) ? 9 : 6;
    const int sz = nt * nct * 512;
    const float* w = src.w[l];
    bf16* dst = wp + OFF[l];
    for (int e = threadIdx.x; e < sz; e += 256) {
        const int j = e & 7;
        const int lane = (e >> 3) & 63;
        const int r = e >> 9;
        const int ct = r % nct, tp = r / nct;
        const int co = ct * 16 + (lane & 15);
        const int kk = ((lane >> 4) << 3) + j;
        float v;
        if (cin == 32) {
            const int ci = kk, ky = tp / 3, kx = tp % 3;
            v = w[((co * 32 + ci) * 3 + ky) * 3 + kx];
        } else {
            const int ci = kk & 15, dxs = kk >> 4;
            const int ky = tp >> 1, kx = (tp & 1) * 2 + dxs;
            v = (kx < 3) ? w[((co * 16 + ci) * 3 + ky) * 3 + kx] : 0.0f;
        }
        dst[e] = __float2bfloat16(v);
    }
}

// ---------------------------------------------------------------------------
// ConvT weight prep: wt[ci][co][a][b] f32 -> A-fragment bf16, m = co*4+ab.
// ---------------------------------------------------------------------------
__global__ __launch_bounds__(256) void prep2_k(
    const float* __restrict__ wt, bf16* __restrict__ wpT)
{
    for (int e = threadIdx.x; e < 4096; e += 256) {
        const int j = e & 7;
        const int lane = (e >> 3) & 63;
        const int mt = e >> 9;
        const int m = mt * 16 + (lane & 15);
        const int k = ((lane >> 4) << 3) + j;     // ci
        wpT[e] = __float2bfloat16(wt[k * 128 + m]);   // m = co*4 + a*2 + b
    }
}

// ---------------------------------------------------------------------------
// x (NCHW f32, 16ch) -> NHWC bf16
// ---------------------------------------------------------------------------
__global__ __launch_bounds__(256) void xtonhwc_k(
    const float* __restrict__ x, bf16* __restrict__ xh)
{
    const int idx = blockIdx.x * 256 + threadIdx.x;   // 4*262144
    const int n = idx >> 18, px = idx & 262143;
    const float* xp = x + (size_t)n * 16 * 262144 + px;
    unsigned short r[16];
    #pragma unroll
    for (int c = 0; c < 16; ++c) r[c] = f2bfu(xp[(size_t)c * 262144]);
    __builtin_memcpy(xh + (size_t)idx * 16, r, 32);
}

// ---------------------------------------------------------------------------
// Implicit-GEMM 3x3 SAME conv with MFMA 16x16x32 bf16, NHWC (unchanged).
// ---------------------------------------------------------------------------
template<int CIN, int COUT, bool RELU, int LW>
__global__ __launch_bounds__(256) void convm_k(
    const bf16* __restrict__ in, const bf16* __restrict__ wp,
    const float* __restrict__ bias, bf16* __restrict__ out)
{
    constexpr int Wd = 1 << LW;
    constexpr int PLANE = Wd * Wd;
    constexpr int NCT = COUT / 16;
    constexpr int NT = (CIN == 32) ? 9 : 6;
    constexpr int CB = CIN * 2;

    const int lane = threadIdx.x & 63;
    const int l4 = lane >> 4;
    const int lm = lane & 15;
    const int wv = threadIdx.x >> 6;
    const int n = blockIdx.y;
    const int pxb = blockIdx.x * 256 + wv * 64;
    const int y = pxb >> LW;
    const int xw = pxb & (Wd - 1);

    bfrag8 afr[NT][NCT];
    #pragma unroll
    for (int tp = 0; tp < NT; ++tp)
        #pragma unroll
        for (int ct = 0; ct < NCT; ++ct)
            __builtin_memcpy(&afr[tp][ct],
                wp + ((size_t)(tp * NCT + ct) * 64 + lane) * 8, 16);

    f32x4 acc[4][NCT];
    #pragma unroll
    for (int ct = 0; ct < NCT; ++ct) {
        const float4 bv = *reinterpret_cast<const float4*>(bias + ct * 16 + l4 * 4);
        #pragma unroll
        for (int t = 0; t < 4; ++t) {
            acc[t][ct][0] = bv.x; acc[t][ct][1] = bv.y;
            acc[t][ct][2] = bv.z; acc[t][ct][3] = bv.w;
        }
    }

    bool okL[4], okR[4];
    #pragma unroll
    for (int t = 0; t < 4; ++t) {
        const int xl = xw + t * 16 + lm;
        okL[t] = (xl != 0)      || (CIN == 16 && lane >= 32);
        okR[t] = (xl != Wd - 1) || (CIN == 16 && lane >= 32);
    }

    int laneoff;
    if (CIN == 32) laneoff = lm * 64 + l4 * 16;
    else           laneoff = lm * 32 + (l4 >> 1) * 32 + (l4 & 1) * 16;

    const char* base = (const char*)in
        + ((size_t)n * PLANE + (size_t)y * Wd + xw) * CB + laneoff;

    #pragma unroll
    for (int ky = 0; ky < 3; ++ky) {
        if ((unsigned)(y + ky - 1) >= (unsigned)Wd) continue;
        const char* rb = base + (ky - 1) * Wd * CB;
        if (CIN == 32) {
            #pragma unroll
            for (int dx = 0; dx < 3; ++dx) {
                #pragma unroll
                for (int t = 0; t < 4; ++t) {
                    uint4 u = *reinterpret_cast<const uint4*>(rb + ((dx - 1) + t * 16) * 64);
                    if (dx == 0 && !okL[t]) { u.x = 0; u.y = 0; u.z = 0; u.w = 0; }
                    if (dx == 2 && !okR[t]) { u.x = 0; u.y = 0; u.z = 0; u.w = 0; }
                    bfrag8 b; __builtin_memcpy(&b, &u, 16);
                    #pragma unroll
                    for (int ct = 0; ct < NCT; ++ct)
                        acc[t][ct] = __builtin_amdgcn_mfma_f32_16x16x32_bf16(
                            afr[ky * 3 + dx][ct], b, acc[t][ct], 0, 0, 0);
                }
            }
        } else {
            #pragma unroll
            for (int p = 0; p < 2; ++p) {
                #pragma unroll
                for (int t = 0; t < 4; ++t) {
                    uint4 u = *reinterpret_cast<const uint4*>(rb + (p ? 32 : -32) + t * 512);
                    if (p == 0 && !okL[t]) { u.x = 0; u.y = 0; u.z = 0; u.w = 0; }
                    if (p == 1 && !okR[t]) { u.x = 0; u.y = 0; u.z = 0; u.w = 0; }
                    bfrag8 b; __builtin_memcpy(&b, &u, 16);
                    #pragma unroll
                    for (int ct = 0; ct < NCT; ++ct)
                        acc[t][ct] = __builtin_amdgcn_mfma_f32_16x16x32_bf16(
                            afr[ky * 2 + p][ct], b, acc[t][ct], 0, 0, 0);
                }
            }
        }
    }

    char* ob = (char*)out + ((size_t)n * PLANE + (size_t)y * Wd + xw) * (COUT * 2);
    #pragma unroll
    for (int t = 0; t < 4; ++t)
        #pragma unroll
        for (int ct = 0; ct < NCT; ++ct) {
            float a0 = acc[t][ct][0], a1 = acc[t][ct][1];
            float a2 = acc[t][ct][2], a3 = acc[t][ct][3];
            if (RELU) {
                a0 = fmaxf(a0, 0.f); a1 = fmaxf(a1, 0.f);
                a2 = fmaxf(a2, 0.f); a3 = fmaxf(a3, 0.f);
            }
            ushort4 pk;
            pk.x = f2bfu(a0); pk.y = f2bfu(a1); pk.z = f2bfu(a2); pk.w = f2bfu(a3);
            *reinterpret_cast<ushort4*>(
                ob + ((size_t)(t * 16 + lm) * COUT + ct * 16 + l4 * 4) * 2) = pk;
        }
}

// ---------------------------------------------------------------------------
// 2x2 maxpool NHWC 32ch (unchanged).
// ---------------------------------------------------------------------------
__global__ __launch_bounds__(256) void pool_k(
    const bf16* __restrict__ in, bf16* __restrict__ out)
{
    const int idx = blockIdx.x * 256 + threadIdx.x;
    const int c8 = (idx & 3) * 8;
    const int opx = idx >> 2;
    const int n = opx >> 16;
    const int p = opx & 65535;
    const int oy = p >> 8, ox = p & 255;
    const char* ip = (const char*)in
        + (((size_t)n * 262144 + (size_t)(2 * oy) * 512 + 2 * ox) * 32 + c8) * 2;
    uint4 ua = *reinterpret_cast<const uint4*>(ip);
    uint4 ub = *reinterpret_cast<const uint4*>(ip + 64);
    uint4 uc = *reinterpret_cast<const uint4*>(ip + 512 * 64);
    uint4 ud = *reinterpret_cast<const uint4*>(ip + 512 * 64 + 64);
    float a[8], b[8], c[8], d[8];
    unpk8(ua, a); unpk8(ub, b); unpk8(uc, c); unpk8(ud, d);
    unsigned short r[8];
    #pragma unroll
    for (int k = 0; k < 8; ++k)
        r[k] = f2bfu(fmaxf(fmaxf(a[k], b[k]), fmaxf(c[k], d[k])));
    __builtin_memcpy((char*)out + (((size_t)n * 65536 + p) * 32 + c8) * 2, r, 16);
}

// ---------------------------------------------------------------------------
// ConvT 2x2 s2 + skip add via MFMA (unchanged, R6).
// ---------------------------------------------------------------------------
__global__ __launch_bounds__(256) void convTm_k(
    const bf16* __restrict__ e, const bf16* __restrict__ wpT,
    const float* __restrict__ bt, bf16* __restrict__ du)
{
    __shared__ float lds[4][16 * 132];
    const int lane = threadIdx.x & 63;
    const int wv = threadIdx.x >> 6;
    const int l4 = lane >> 4, lm = lane & 15;
    const int n = blockIdx.y;
    const int row = blockIdx.x;
    const int j0 = wv * 64;

    bfrag8 afr[8];
    #pragma unroll
    for (int mt = 0; mt < 8; ++mt)
        __builtin_memcpy(&afr[mt], wpT + ((size_t)(mt * 64 + lane)) * 8, 16);

    float bco[8];
    #pragma unroll
    for (int mt = 0; mt < 8; ++mt) bco[mt] = bt[mt * 4 + l4];

    const char* ep = (const char*)e + ((size_t)n * 65536 + (size_t)row * 256 + j0) * 64;
    float* L = lds[wv];

    const int ra = lane >> 5;
    const int ru = lane & 31;
    const int rj = ru >> 1;
    const int rb = ru & 1;

    #pragma unroll 1
    for (int nt = 0; nt < 4; ++nt) {
        bfrag8 bf;
        __builtin_memcpy(&bf, ep + (nt * 16 + lm) * 64 + l4 * 16, 16);

        #pragma unroll
        for (int mt = 0; mt < 8; ++mt) {
            f32x4 acc;
            acc[0] = bco[mt]; acc[1] = bco[mt]; acc[2] = bco[mt]; acc[3] = bco[mt];
            acc = __builtin_amdgcn_mfma_f32_16x16x32_bf16(afr[mt], bf, acc, 0, 0, 0);
            float4 st; st.x = acc[0]; st.y = acc[1]; st.z = acc[2]; st.w = acc[3];
            *reinterpret_cast<float4*>(L + lm * 132 + mt * 16 + l4 * 4) = st;
        }
        __syncthreads();

        {
            const float* Ls = L + rj * 132 + ra * 2 + rb;
            char* dp = (char*)du
                + (((size_t)n * 262144
                    + (size_t)(2 * row + ra) * 512
                    + (size_t)(2 * (j0 + nt * 16 + rj) + rb)) * 32) * 2;
            float add[32];
            #pragma unroll
            for (int co = 0; co < 32; ++co) add[co] = Ls[co * 4];
            #pragma unroll
            for (int q = 0; q < 4; ++q) {
                uint4 u = *reinterpret_cast<const uint4*>(dp + q * 16);
                float dv[8]; unpk8(u, dv);
                unsigned short r[8];
                #pragma unroll
                for (int k = 0; k < 8; ++k) r[k] = f2bfu(dv[k] + add[q * 8 + k]);
                __builtin_memcpy(dp + q * 16, r, 16);
            }
        }
        __syncthreads();
    }
}

// ---------------------------------------------------------------------------
// S precompute: S(p) = sum_i cw_i * v_i(p)^2 over the 27 combined channels.
// Runs after conv8 (feats ready); writes into the then-dead du region.
// ---------------------------------------------------------------------------
__global__ __launch_bounds__(256) void sprep_k(
    const float* __restrict__ xin, const bf16* __restrict__ feats,
    const float* __restrict__ fp, float* __restrict__ S)
{
    constexpr int PLANE = 512 * 512;
    const int pix = blockIdx.x * 256 + threadIdx.x;
    const int n = blockIdx.y;

    const float* xb = xin + (size_t)n * 16 * PLANE + pix;
    const char* fb = (const char*)feats + ((size_t)n * PLANE + pix) * 32;

    float s = 0.0f;
    #pragma unroll
    for (int i = 0; i < 11; ++i) {
        const float v = xb[(size_t)i * PLANE];
        s = fmaf(fp[i], v * v, s);
    }
    uint4 u0 = *reinterpret_cast<const uint4*>(fb);
    uint4 u1 = *reinterpret_cast<const uint4*>(fb + 16);
    float fv[16];
    unpk8(u0, fv); unpk8(u1, fv + 8);
    #pragma unroll
    for (int i = 0; i < 16; ++i)
        s = fmaf(fp[11 + i], fv[i] * fv[i], s);

    S[(size_t)n * PLANE + pix] = s;
}

// ---------------------------------------------------------------------------
// Bilateral, factored form:
//   logw(p,q) = S_q - 2 * sum_i g_i(p) v_i(q) + S_p + spatial
// with g_i = cw_i * v_i(p). S_q loaded (1 f32); cross = 27 FMA; num = 11 FMA.
// ---------------------------------------------------------------------------
__global__ __launch_bounds__(256) void bil_k(
    const float* __restrict__ xin, const bf16* __restrict__ feats,
    const float* __restrict__ Sbuf, const float* __restrict__ fp,
    float* __restrict__ out)
{
    constexpr int PLANE = 512 * 512;
    const int pix = blockIdx.x * 256 + threadIdx.x;
    const int n = blockIdx.y;
    const int y = pix >> 9, xx = pix & 511;

    const float sy = fp[27], sx = fp[28];

    const float* xb = xin + (size_t)n * 16 * PLANE + pix;
    const char* fb = (const char*)feats + ((size_t)n * PLANE + pix) * 32;
    const float* Sb = Sbuf + (size_t)n * PLANE + pix;

    // center values, g = cw*c, S_p = sum g*c
    float g[27];
    float Sp = 0.0f;
    #pragma unroll
    for (int i = 0; i < 11; ++i) {
        const float c = xb[(size_t)i * PLANE];
        g[i] = fp[i] * c;
        Sp = fmaf(g[i], c, Sp);
    }
    {
        uint4 u0 = *reinterpret_cast<const uint4*>(fb);
        uint4 u1 = *reinterpret_cast<const uint4*>(fb + 16);
        float cf[16];
        unpk8(u0, cf); unpk8(u1, cf + 8);
        #pragma unroll
        for (int i = 0; i < 16; ++i) {
            g[11 + i] = fp[11 + i] * cf[i];
            Sp = fmaf(g[11 + i], cf[i], Sp);
        }
    }

    float num[11];
    #pragma unroll
    for (int i = 0; i < 11; ++i) num[i] = 0.0f;
    float den = 0.0f;

    #pragma unroll
    for (int dy = -2; dy <= 2; ++dy) {
        const int yy = y + 2 * dy;
        if ((unsigned)yy > 511u) continue;            // uniform per block
        const float baseY = fmaf(sy, (float)(4 * dy * dy), Sp);
        #pragma unroll
        for (int dx = -2; dx <= 2; ++dx) {
            const int xv = xx + 2 * dx;
            if ((unsigned)xv > 511u) continue;        // edge lanes only
            const int off = dy * 1024 + dx * 2;
            const float base = fmaf(sx, (float)(4 * dx * dx), baseY) + Sb[off];

            float cross;
            float shv[11];
            {
                const float s0 = xb[(size_t)0 * PLANE + off];
                shv[0] = s0;
                cross = g[0] * s0;
            }
            #pragma unroll
            for (int i = 1; i < 11; ++i) {
                const float s = xb[(size_t)i * PLANE + off];
                shv[i] = s;
                cross = fmaf(g[i], s, cross);
            }
            const char* fq = fb + (ptrdiff_t)off * 32;
            uint4 u0 = *reinterpret_cast<const uint4*>(fq);
            uint4 u1 = *reinterpret_cast<const uint4*>(fq + 16);
            float fv[16];
            unpk8(u0, fv); unpk8(u1, fv + 8);
            #pragma unroll
            for (int i = 0; i < 16; ++i)
                cross = fmaf(g[11 + i], fv[i], cross);

            const float w = __expf(fmaf(-2.0f, cross, base));
            #pragma unroll
            for (int i = 0; i < 11; ++i) num[i] = fmaf(w, shv[i], num[i]);
            den += w;
        }
    }

    const float inv = 1.0f / den;
    float* ob = out + (size_t)n * 11 * PLANE + pix;
    #pragma unroll
    for (int i = 0; i < 11; ++i) ob[(size_t)i * PLANE] = num[i] * inv;
}

// ---------------------------------------------------------------------------
extern "C" void kernel_launch(void* const* d_in, const int* in_sizes, int n_in,
                              void* d_out, int out_size, void* d_ws, size_t ws_size,
                              hipStream_t stream)
{
    const float* x = (const float*)d_in[0];
    const float* Wv[9];
    const float* Bv[9];
    if (in_sizes[2] == 16) {
        for (int i = 0; i < 9; ++i) {
            Wv[i] = (const float*)d_in[1 + 2 * i];
            Bv[i] = (const float*)d_in[2 + 2 * i];
        }
    } else {
        for (int i = 0; i < 9; ++i) {
            Wv[i] = (const float*)d_in[1 + i];
            Bv[i] = (const float*)d_in[10 + i];
        }
    }
    const float* wt = (const float*)d_in[19];
    const float* bt = (const float*)d_in[20];
    const float* fp = (const float*)d_in[21];
    float* out = (float*)d_out;

    constexpr size_t MiB = 1ull << 20;
    char* ws = (char*)d_ws;

    bf16* wp  = (bf16*)(ws + 4096);
    bf16* wpT = (bf16*)(ws + 256 * 1024);
    bf16 *xh, *du, *bufA, *bufB;
    if (ws_size >= 165 * MiB) {
        xh   = (bf16*)(ws + 1 * MiB);
        du   = (bf16*)(ws + 34 * MiB);
        bufA = (bf16*)(ws + 99 * MiB);
        bufB = (bf16*)(ws + 132 * MiB);
    } else if (ws_size >= 132 * MiB) {
        xh   = (bf16*)(ws + 1 * MiB);
        du   = (bf16*)(ws + 34 * MiB);
        bufA = (bf16*)(ws + 99 * MiB);
        bufB = xh;
    } else {
        xh   = (bf16*)((char*)d_out + 256);
        du   = (bf16*)(ws + 1 * MiB);
        bufA = (bf16*)(ws + 66 * MiB);
        bufB = xh;
    }
    float* Sbuf = (float*)du;   // du is dead after conv6; reused for S (4 MiB)

    WSrc srcs;
    for (int i = 0; i < 9; ++i) srcs.w[i] = Wv[i];

    prep_k<<<9, 256, 0, stream>>>(srcs, wp);
    prep2_k<<<1, 256, 0, stream>>>(wt, wpT);
    xtonhwc_k<<<4096, 256, 0, stream>>>(x, xh);

    const dim3 blk(256);
    const dim3 g512(1024, 4), g256(256, 4);

    convm_k<16, 16, true,  9><<<g512, blk, 0, stream>>>(xh,   wp + 0,     Bv[0], bufA);
    convm_k<16, 16, true,  9><<<g512, blk, 0, stream>>>(bufA, wp + 3072,  Bv[1], bufB);
    convm_k<16, 32, false, 9><<<g512, blk, 0, stream>>>(bufB, wp + 6144,  Bv[2], du);

    pool_k<<<4096, blk, 0, stream>>>(du, bufA);
    convm_k<32, 32, true, 8><<<g256, blk, 0, stream>>>(bufA, wp + 12288, Bv[3], bufB);
    convm_k<32, 32, true, 8><<<g256, blk, 0, stream>>>(bufB, wp + 21504, Bv[4], bufA);
    convm_k<32, 32, true, 8><<<g256, blk, 0, stream>>>(bufA, wp + 30720, Bv[5], bufB);

    convTm_k<<<g256, blk, 0, stream>>>(bufB, wpT, bt, du);

    convm_k<32, 16, true,  9><<<g512, blk, 0, stream>>>(du,   wp + 39936, Bv[6], bufA);
    convm_k<16, 16, true,  9><<<g512, blk, 0, stream>>>(bufA, wp + 44544, Bv[7], bufB);
    convm_k<16, 16, false, 9><<<g512, blk, 0, stream>>>(bufB, wp + 47616, Bv[8], bufA);

    // S pass (du dead now), then factored bilateral
    sprep_k<<<g512, blk, 0, stream>>>(x, bufA, fp, Sbuf);
    bil_k<<<g512, blk, 0, stream>>>(x, bufA, Sbuf, fp, out);

    (void)n_in; (void)out_size;
}